// Round 6
// baseline (58.655 us; speedup 1.0000x reference)
//
#include <hip/hip_runtime.h>
#include <hip/hip_bf16.h>
#include <math.h>

// Problem constants (from reference)
#define R_CHK   144
#define N_VAR   576
#define BATCH   512
#define ITERS   3
#define NLEV    16
#define ROW_DEG 15
#define N_EDGE  (R_CHK * ROW_DEG)   // 2160
#define NWORDS  9                    // 576 / 64
#define DEG_PAD 16                   // padded max column degree
#define NCOLP   9                    // columns per lane (576/64)
#define NROWP   3                    // row passes per lane (ceil(144/64))

// ---------------------------------------------------------------------------
// K1: one wave per row -> 9 ballot words + row edge-column list.
// ---------------------------------------------------------------------------
__launch_bounds__(64)
__global__ void k1_bitmask(const float* __restrict__ H,
                           unsigned long long* __restrict__ bits,
                           int* __restrict__ edge_cols) {
    const int i    = blockIdx.x;
    const int lane = threadIdx.x;

    float h[NWORDS];
#pragma unroll
    for (int s = 0; s < NWORDS; ++s) h[s] = H[i * N_VAR + s * 64 + lane];

    unsigned long long m[NWORDS];
#pragma unroll
    for (int s = 0; s < NWORDS; ++s) m[s] = __ballot(h[s] > 0.5f);

#pragma unroll
    for (int s = 0; s < NWORDS; ++s)
        if (lane == s) bits[i * NWORDS + s] = m[s];

    if (lane == 0) {
        int k = 0;
#pragma unroll
        for (int s = 0; s < NWORDS; ++s) {
            unsigned long long mm = m[s];
            while (mm) {
                int b = __ffsll((long long)mm) - 1;
                if (k < ROW_DEG) edge_cols[i * ROW_DEG + k] = s * 64 + b;
                ++k;
                mm &= mm - 1;
            }
        }
    }
}

// ---------------------------------------------------------------------------
// K2: bitmask -> fixed-degree column table (ascending row order, padded with
// dummy edge id N_EDGE which maps to a zero slot in decode's sE).
// ---------------------------------------------------------------------------
__launch_bounds__(N_VAR)
__global__ void k2_coltab(const unsigned long long* __restrict__ bits,
                          int* __restrict__ col_edge) {
    __shared__ unsigned long long sb[R_CHK * NWORDS];   // 10368 B
    __shared__ int spref[R_CHK * NWORDS];               //  5184 B

    const int t = threadIdx.x;   // 576 threads

    for (int e = t; e < R_CHK * NWORDS; e += N_VAR) sb[e] = bits[e];
    __syncthreads();

    for (int idx = t; idx < R_CHK * NWORDS; idx += N_VAR) {
        int i = idx / NWORDS, w = idx % NWORDS;
        int p = 0;
        for (int u = 0; u < w; ++u) p += __popcll(sb[i * NWORDS + u]);
        spref[idx] = p;
    }
    __syncthreads();

    const int w   = t >> 6;
    const int bit = t & 63;
    const unsigned long long vmask   = 1ull << bit;
    const unsigned long long lowmask = vmask - 1ull;
    int n = 0;
    for (int i0 = 0; i0 < R_CHK; i0 += 16) {
        unsigned long long mw[16];
        int pf[16];
#pragma unroll
        for (int j = 0; j < 16; ++j) {
            mw[j] = sb[(i0 + j) * NWORDS + w];
            pf[j] = spref[(i0 + j) * NWORDS + w];
        }
#pragma unroll
        for (int j = 0; j < 16; ++j) {
            if (mw[j] & vmask) {
                int rank = pf[j] + __popcll(mw[j] & lowmask);
                if (n < DEG_PAD) col_edge[t * DEG_PAD + n] = (i0 + j) * ROW_DEG + rank;
                ++n;
            }
        }
    }
    for (int j = n; j < DEG_PAD; ++j) col_edge[t * DEG_PAD + j] = N_EDGE; // pad
}

// ---------------------------------------------------------------------------
// Decode: ONE BATCH PER WAVE. 64-thread blocks, no __syncthreads at all.
// All tables/messages in registers; quantizer is a pure-VALU cndmask chain.
// ---------------------------------------------------------------------------
__launch_bounds__(64, 1)
__global__ void decode_kernel(const float* __restrict__ r,
                              const float* __restrict__ alpha,
                              const float* __restrict__ beta,
                              const float* __restrict__ eta,
                              const float* __restrict__ qkg,
                              const int* __restrict__ edge_cols,
                              const int* __restrict__ col_edge,
                              float* __restrict__ out) {
    __shared__ float sE[N_EDGE + 1];  // +1: zero slot for padded column reads
    __shared__ float sr[N_VAR];       // only for iter-0 M gather
    __shared__ float st[N_VAR];       // r + colsum (cross-lane)

    const int b    = blockIdx.x;
    const int lane = threadIdx.x;     // 0..63

    // Quantizer tables in registers.
    float qk[NLEV], bnd[NLEV - 1];
#pragma unroll
    for (int j = 0; j < NLEV; ++j) qk[j] = qkg[j];
#pragma unroll
    for (int j = 0; j < NLEV - 1; ++j) bnd[j] = 0.5f * (qk[j] + qk[j + 1]);

    // Exact searchsorted: monotone predicate -> cndmask chain, bit-identical
    // to idx = count(y > bnd[j]); result = qk[idx].
    auto QZ = [&](float y) -> float {
        float q = qk[0];
#pragma unroll
        for (int j = 0; j < NLEV - 1; ++j) q = (y > bnd[j]) ? qk[j + 1] : q;
        return q;
    };
    const float q0 = QZ(0.0f);        // quantization of exact zero (hoisted)

    float av[ITERS], bv[ITERS], ev[ITERS];
#pragma unroll
    for (int i = 0; i < ITERS; ++i) { av[i] = alpha[i]; bv[i] = beta[i]; ev[i] = eta[i]; }

    // Register-resident column table (lane owns columns lane+64c).
    int ce[NCOLP][DEG_PAD];
#pragma unroll
    for (int c = 0; c < NCOLP; ++c) {
        const int4* p4 = (const int4*)(col_edge + (lane + 64 * c) * DEG_PAD);
#pragma unroll
        for (int j = 0; j < 4; ++j) {
            int4 v = p4[j];
            ce[c][4 * j + 0] = v.x; ce[c][4 * j + 1] = v.y;
            ce[c][4 * j + 2] = v.z; ce[c][4 * j + 3] = v.w;
        }
    }

    // Row column-ids (lane owns rows lane, lane+64, lane+128[<16]).
    int cols[NROWP][ROW_DEG];
#pragma unroll
    for (int p = 0; p < NROWP; ++p) {
        const int row = lane + 64 * p;
        if (row < R_CHK) {
#pragma unroll
            for (int k = 0; k < ROW_DEG; ++k) cols[p][k] = edge_cols[row * ROW_DEG + k];
        }
    }

    // Channel values: registers for own columns, LDS copy for iter-0 gather.
    float rv[NCOLP];
#pragma unroll
    for (int c = 0; c < NCOLP; ++c) {
        rv[c] = r[b * N_VAR + lane + 64 * c];
        sr[lane + 64 * c] = rv[c];
    }
    if (lane == 0) sE[N_EDGE] = 0.0f;
    __builtin_amdgcn_wave_barrier();

    float M[NROWP][ROW_DEG], Eq[NROWP][ROW_DEG];
#pragma unroll
    for (int p = 0; p < NROWP; ++p) {
        const int row = lane + 64 * p;
        if (row < R_CHK) {
#pragma unroll
            for (int k = 0; k < ROW_DEG; ++k) M[p][k] = sr[cols[p][k]];   // M = H*r
        }
    }

#pragma unroll
    for (int it = 0; it < ITERS; ++it) {
        const float a = av[it], bta = bv[it], et = ev[it];

        // ---- fused M-update from previous iteration (eta_{it-1}) ---------
        if (it > 0) {
            const float etp = ev[it - 1];
#pragma unroll
            for (int p = 0; p < NROWP; ++p) {
                const int row = lane + 64 * p;
                if (row < R_CHK) {
#pragma unroll
                    for (int k = 0; k < ROW_DEG; ++k) {
                        float x = st[cols[p][k]] - Eq[p][k];   // (r+col) - E
                        M[p][k] = QZ(etp * x);
                    }
                }
            }
        }

        // ---- row phase ----------------------------------------------------
#pragma unroll
        for (int p = 0; p < NROWP; ++p) {
            const int row = lane + 64 * p;
            if (row < R_CHK) {
                float sg[ROW_DEG];
#pragma unroll
                for (int k = 0; k < ROW_DEG; ++k)
                    sg[k] = (M[p][k] > 0.0f) ? 1.0f : ((M[p][k] < 0.0f) ? -1.0f : 0.0f);
                float t0 = sg[0] * sg[1],  t1 = sg[2] * sg[3];
                float t2 = sg[4] * sg[5],  t3 = sg[6] * sg[7];
                float t4 = sg[8] * sg[9],  t5 = sg[10] * sg[11];
                float t6 = sg[12] * sg[13], t7 = sg[14];
                float u0 = t0 * t1, u1 = t2 * t3, u2 = t4 * t5, u3 = t6 * t7;
                const float prod = (u0 * u1) * (u2 * u3);

                float a1[8], a2[8];
#pragma unroll
                for (int k = 0; k < 7; ++k) {
                    float x = fabsf(M[p][2 * k]), y = fabsf(M[p][2 * k + 1]);
                    a1[k] = fminf(x, y); a2[k] = fmaxf(x, y);
                }
                a1[7] = fabsf(M[p][14]); a2[7] = INFINITY;
#pragma unroll
                for (int s = 4; s >= 1; s >>= 1) {
#pragma unroll
                    for (int k = 0; k < 4; ++k) {
                        if (k < s) {
                            float lo = fminf(a1[k], a1[k + s]);
                            float hi = fminf(fmaxf(a1[k], a1[k + s]), fminf(a2[k], a2[k + s]));
                            a1[k] = lo; a2[k] = hi;
                        }
                    }
                }
                const float m1 = a1[0], m2 = a2[0];

                // E candidates: E in {ap*g1, -(ap*g1), ap*g2, -(ap*g2), +-0},
                // all bit-exact vs ((a*prod)*sg)*fmax(mexcl-beta,0).
                const float ap = a * prod;
                const float g1 = fmaxf(m1 - bta, 0.0f);
                const float g2 = fmaxf(m2 - bta, 0.0f);
                const float y1 = et * (ap * g1);
                const float y2 = et * (ap * g2);
                const float c1p = QZ(y1), c1m = QZ(-y1);
                const float c2p = QZ(y2), c2m = QZ(-y2);

#pragma unroll
                for (int k = 0; k < ROW_DEG; ++k) {
                    const bool ismin = (fabsf(M[p][k]) == m1);   // -> mexcl = m2
                    float cp = ismin ? c2p : c1p;
                    float cm = ismin ? c2m : c1m;
                    float q = (sg[k] > 0.0f) ? cp : cm;
                    q = (sg[k] == 0.0f) ? q0 : q;
                    Eq[p][k] = q;
                    sE[row * ROW_DEG + k] = q;
                }
            }
        }
        __builtin_amdgcn_wave_barrier();

        // ---- column phase (ascending row order; pads add exact +0.0) ------
#pragma unroll
        for (int c = 0; c < NCOLP; ++c) {
            float s = 0.0f;
#pragma unroll
            for (int j = 0; j < DEG_PAD; ++j) s += sE[ce[c][j]];
            const float stv = rv[c] + s;
            st[lane + 64 * c] = stv;
            if (it == ITERS - 1) out[b * N_VAR + lane + 64 * c] = stv;
        }
        __builtin_amdgcn_wave_barrier();
    }
}

// ---------------------------------------------------------------------------
extern "C" void kernel_launch(void* const* d_in, const int* in_sizes, int n_in,
                              void* d_out, int out_size, void* d_ws, size_t ws_size,
                              hipStream_t stream) {
    const float* r     = (const float*)d_in[0];
    const float* alpha = (const float*)d_in[1];
    const float* beta  = (const float*)d_in[2];
    const float* eta   = (const float*)d_in[3];
    const float* qk    = (const float*)d_in[4];
    const float* H     = (const float*)d_in[5];
    float* out = (float*)d_out;

    // workspace layout (bits first: 8B aligned)
    unsigned long long* bits = (unsigned long long*)d_ws;     // 1296 u64
    int* edge_cols = (int*)(bits + R_CHK * NWORDS);           // 2160 ints
    int* col_edge  = edge_cols + N_EDGE;                      // 576*16 ints

    k1_bitmask<<<R_CHK, 64, 0, stream>>>(H, bits, edge_cols);
    k2_coltab<<<1, N_VAR, 0, stream>>>(bits, col_edge);
    decode_kernel<<<BATCH, 64, 0, stream>>>(r, alpha, beta, eta, qk,
                                            edge_cols, col_edge, out);
}

// Round 7
// 40.968 us; speedup vs baseline: 1.4317x; 1.4317x over previous
//
#include <hip/hip_runtime.h>
#include <hip/hip_bf16.h>
#include <math.h>

// Problem constants (from reference)
#define R_CHK   144
#define N_VAR   576
#define BATCH   512
#define ITERS   3
#define NLEV    16
#define ROW_DEG 15
#define N_EDGE  (R_CHK * ROW_DEG)    // 2160
#define NWORDS  9                    // 576 / 64
#define DEG_PAD 16                   // padded max column degree
#define SLOT    16                   // sE row stride (slot 15 = zero pad)
#define NTHR    576                  // 9 waves

// ---------------------------------------------------------------------------
// K12: fused index build. One 576-thread block.
//  - wave w ballot-compresses rows 16w..16w+15 of H into a 144x9 u64 bitmask
//  - per-row edge column lists (ascending cols) + word-prefix popcounts
//  - per-column u16 edge-slot table (ascending rows), ids = row*16 + rank,
//    padded with 15 (sE slot 15 of row 0 always holds 0.0f)
// ---------------------------------------------------------------------------
__launch_bounds__(NTHR)
__global__ void k12_index(const float* __restrict__ H,
                          int* __restrict__ edge_cols,
                          unsigned short* __restrict__ col_pack) {
    __shared__ unsigned long long sb[R_CHK * NWORDS];   // 10368 B
    __shared__ int spref[R_CHK * NWORDS];               //  5184 B

    const int t    = threadIdx.x;
    const int w    = t >> 6;
    const int lane = t & 63;

    // Phase 0: bitmask via ballots, 4 rows' loads in flight per chunk.
    for (int j0 = 0; j0 < 16; j0 += 4) {
        float h[4][NWORDS];
#pragma unroll
        for (int jj = 0; jj < 4; ++jj)
#pragma unroll
            for (int s = 0; s < NWORDS; ++s)
                h[jj][s] = H[(16 * w + j0 + jj) * N_VAR + s * 64 + lane];
#pragma unroll
        for (int jj = 0; jj < 4; ++jj)
#pragma unroll
            for (int s = 0; s < NWORDS; ++s) {
                unsigned long long m = __ballot(h[jj][s] > 0.5f);
                if (lane == s) sb[(16 * w + j0 + jj) * NWORDS + s] = m;
            }
    }
    __syncthreads();

    // Phase 1: per-row extraction + word-prefix popcounts.
    if (t < R_CHK) {
        int k = 0, p = 0;
#pragma unroll
        for (int s = 0; s < NWORDS; ++s) {
            unsigned long long m = sb[t * NWORDS + s];
            spref[t * NWORDS + s] = p;
            p += __popcll(m);
            while (m) {
                int bpos = __ffsll((long long)m) - 1;
                if (k < ROW_DEG) edge_cols[t * ROW_DEG + k] = s * 64 + bpos;
                ++k;
                m &= m - 1;
            }
        }
    }
    __syncthreads();

    // Phase 2: per-column table (ascending row order), u16 slot ids.
    {
        const int wq  = t >> 6;
        const int bit = t & 63;
        const unsigned long long vmask   = 1ull << bit;
        const unsigned long long lowmask = vmask - 1ull;
        int n = 0;
        for (int i0 = 0; i0 < R_CHK; i0 += 16) {
            unsigned long long mw[16];
            int pf[16];
#pragma unroll
            for (int j = 0; j < 16; ++j) {
                mw[j] = sb[(i0 + j) * NWORDS + wq];
                pf[j] = spref[(i0 + j) * NWORDS + wq];
            }
#pragma unroll
            for (int j = 0; j < 16; ++j) {
                if (mw[j] & vmask) {
                    int rank = pf[j] + __popcll(mw[j] & lowmask);
                    if (n < DEG_PAD)
                        col_pack[t * DEG_PAD + n] =
                            (unsigned short)((i0 + j) * SLOT + rank);
                    ++n;
                }
            }
        }
        for (int j = (n < DEG_PAD ? n : DEG_PAD); j < DEG_PAD; ++j)
            col_pack[t * DEG_PAD + j] = 15;   // pad -> sE[15] == 0.0f
    }
}

// ---------------------------------------------------------------------------
// Decode: one batch per 576-thread block. 4 threads per check row (4 edge
// slots each, slot 15 is a zero pad); row reduce via 4-lane shfl_xor
// butterfly; one column per thread. 2 barriers/iter.
// ---------------------------------------------------------------------------
__launch_bounds__(NTHR, 5)
__global__ void decode_kernel(const float* __restrict__ r,
                              const float* __restrict__ alpha,
                              const float* __restrict__ beta,
                              const float* __restrict__ eta,
                              const float* __restrict__ qkg,
                              const int* __restrict__ edge_cols,
                              const int* __restrict__ col_pack,
                              float* __restrict__ out) {
    __shared__ float sE[R_CHK * SLOT];   // 9216 B, slot 15 of each row = 0
    __shared__ float st[N_VAR];          // r (init), then r + colsum

    const int b   = blockIdx.x;
    const int t   = threadIdx.x;
    const int row = t >> 2;              // 0..143
    const int g   = t & 3;               // position of this thread in its row

    // Quantizer: exact searchsorted predicate; table lookup via __shfl.
    const float qv = qkg[t & 15];        // lane L holds qk[L&15]
    float bnd[NLEV - 1];
#pragma unroll
    for (int j = 0; j < NLEV - 1; ++j) bnd[j] = 0.5f * (qkg[j] + qkg[j + 1]);
    auto QI = [&](float y) -> int {
        int idx = 0;
#pragma unroll
        for (int j = 0; j < NLEV - 1; ++j) idx += (y > bnd[j]) ? 1 : 0;
        return idx;
    };
    const float q0 = __shfl(qv, QI(0.0f));   // quantize(exact 0), hoisted

    float av[ITERS], bv[ITERS], ev[ITERS];
#pragma unroll
    for (int i = 0; i < ITERS; ++i) { av[i] = alpha[i]; bv[i] = beta[i]; ev[i] = eta[i]; }

    // Column table (u16 packed -> 8 ints in registers).
    int pp[8];
    {
        const int4* p4 = (const int4*)col_pack + t * 2;
        int4 a0 = p4[0], a1 = p4[1];
        pp[0] = a0.x; pp[1] = a0.y; pp[2] = a0.z; pp[3] = a0.w;
        pp[4] = a1.x; pp[5] = a1.y; pp[6] = a1.z; pp[7] = a1.w;
    }

    // This thread's 4 edge slots' variable columns (pad -> 0, unused).
    int cols[4];
#pragma unroll
    for (int j = 0; j < 4; ++j) {
        const int ke = 4 * g + j;
        cols[j] = (ke < ROW_DEG) ? edge_cols[row * ROW_DEG + ke] : 0;
    }

    const float rv = r[b * N_VAR + t];
    st[t] = rv;
    __syncthreads();

    float M[4], Eq[4];
#pragma unroll
    for (int j = 0; j < 4; ++j) M[j] = st[cols[j]];   // M = H*r (st == r)

#pragma unroll
    for (int it = 0; it < ITERS; ++it) {
        const float a = av[it], bta = bv[it], et = ev[it];

        // ---- fused M-update from previous iteration (eta_{it-1}) ---------
        if (it > 0) {
            const float etp = ev[it - 1];
#pragma unroll
            for (int j = 0; j < 4; ++j) {
                float x = st[cols[j]] - Eq[j];    // (r+col) - E
                M[j] = __shfl(qv, QI(etp * x));
            }
        }

        // ---- row phase: signs, |M|, local min2, 4-lane butterfly ---------
        float sg[4], ab[4];
#pragma unroll
        for (int j = 0; j < 4; ++j) {
            const int ke = 4 * g + j;
            float m = M[j];
            float s = (m > 0.0f) ? 1.0f : ((m < 0.0f) ? -1.0f : 0.0f);
            sg[j] = (ke < ROW_DEG) ? s : 1.0f;
            ab[j] = (ke < ROW_DEG) ? fabsf(m) : INFINITY;
        }
        float pl = (sg[0] * sg[1]) * (sg[2] * sg[3]);
        float l1a = fminf(ab[0], ab[1]), l2a = fmaxf(ab[0], ab[1]);
        float l1b = fminf(ab[2], ab[3]), l2b = fmaxf(ab[2], ab[3]);
        float m1 = fminf(l1a, l1b);
        float m2 = fminf(fmaxf(l1a, l1b), fminf(l2a, l2b));
        {
            float o1 = __shfl_xor(m1, 1), o2 = __shfl_xor(m2, 1);
            float n1 = fminf(m1, o1);
            float n2 = fminf(fmaxf(m1, o1), fminf(m2, o2));
            m1 = n1; m2 = n2;
            float op = __shfl_xor(pl, 1); pl *= op;
            o1 = __shfl_xor(m1, 2); o2 = __shfl_xor(m2, 2);
            n1 = fminf(m1, o1);
            n2 = fminf(fmaxf(m1, o1), fminf(m2, o2));
            m1 = n1; m2 = n2;
            op = __shfl_xor(pl, 2); pl *= op;
        }

        // ---- E candidates + per-edge select + quantize --------------------
        const float ap = a * pl;
        const float g1 = fmaxf(m1 - bta, 0.0f);
        const float g2 = fmaxf(m2 - bta, 0.0f);
        const float y1 = et * (ap * g1);
        const float y2 = et * (ap * g2);
        const float c1p = __shfl(qv, QI(y1)), c1m = __shfl(qv, QI(-y1));
        const float c2p = __shfl(qv, QI(y2)), c2m = __shfl(qv, QI(-y2));
#pragma unroll
        for (int j = 0; j < 4; ++j) {
            const int ke = 4 * g + j;
            const bool ismin = (ab[j] == m1);          // -> mexcl = m2
            float cp = ismin ? c2p : c1p;
            float cm = ismin ? c2m : c1m;
            float q = (sg[j] > 0.0f) ? cp : cm;
            q = (sg[j] == 0.0f) ? q0 : q;
            q = (ke < ROW_DEG) ? q : 0.0f;             // pad slot stays 0
            Eq[j] = q;
            sE[row * SLOT + ke] = q;
        }
        __syncthreads();

        // ---- column phase: ascending-row fixed-degree sum -----------------
        {
            float s = 0.0f;
#pragma unroll
            for (int j = 0; j < DEG_PAD; ++j) {
                int id = (pp[j >> 1] >> (16 * (j & 1))) & 0xffff;
                s += sE[id];
            }
            float stv = rv + s;
            st[t] = stv;
            if (it == ITERS - 1) out[b * N_VAR + t] = stv;
        }
        if (it < ITERS - 1) __syncthreads();
    }
}

// ---------------------------------------------------------------------------
extern "C" void kernel_launch(void* const* d_in, const int* in_sizes, int n_in,
                              void* d_out, int out_size, void* d_ws, size_t ws_size,
                              hipStream_t stream) {
    const float* r     = (const float*)d_in[0];
    const float* alpha = (const float*)d_in[1];
    const float* beta  = (const float*)d_in[2];
    const float* eta   = (const float*)d_in[3];
    const float* qk    = (const float*)d_in[4];
    const float* H     = (const float*)d_in[5];
    float* out = (float*)d_out;

    // workspace layout (16B-aligned sections)
    int* edge_cols = (int*)d_ws;                                   // 2160 ints (8640 B)
    unsigned short* col_pack = (unsigned short*)(edge_cols + N_EDGE); // 576*16 u16

    k12_index<<<1, NTHR, 0, stream>>>(H, edge_cols, col_pack);
    decode_kernel<<<BATCH, NTHR, 0, stream>>>(r, alpha, beta, eta, qk,
                                              edge_cols, (const int*)col_pack, out);
}